// Round 1
// baseline (2071.570 us; speedup 1.0000x reference)
//
#include <hip/hip_runtime.h>
#include <hip/hip_bf16.h>
#include <stdint.h>

#define NH 10
#define NB 32768
#define ND 1024

typedef __bf16 bf16x8 __attribute__((ext_vector_type(8)));
typedef float f32x4 __attribute__((ext_vector_type(4)));

typedef const __attribute__((address_space(1))) unsigned int* gas_ptr;
typedef __attribute__((address_space(3))) unsigned int* las_ptr;

__device__ __forceinline__ void load16_lds(const void* g, void* l) {
    __builtin_amdgcn_global_load_lds((gas_ptr)g, (las_ptr)l, 16, 0, 0);
}

// ---------------- K1: transpose + convert W21/W22 (H,1024,1024 f32 [o][p]) -> bf16 [p][o]
__global__ void wt_kernel(const float* __restrict__ W21, const float* __restrict__ W22,
                          __hip_bfloat16* __restrict__ W21T, __hip_bfloat16* __restrict__ W22T) {
    int z = blockIdx.z;
    const float* src;
    __hip_bfloat16* dst;
    if (z < NH) { src = W21 + (size_t)z * ND * ND; dst = W21T + (size_t)z * ND * ND; }
    else        { src = W22 + (size_t)(z - NH) * ND * ND; dst = W22T + (size_t)(z - NH) * ND * ND; }
    int o0 = blockIdx.x * 32, p0 = blockIdx.y * 32;
    __shared__ float tile[32][33];
    int t = threadIdx.x;
    int r = t >> 3, cg = (t & 7) << 2;
    float4 v = *(const float4*)&src[(size_t)(o0 + r) * ND + p0 + cg];
    tile[r][cg + 0] = v.x; tile[r][cg + 1] = v.y; tile[r][cg + 2] = v.z; tile[r][cg + 3] = v.w;
    __syncthreads();
    union { __hip_bfloat16 h[4]; uint2 u; } pk;
#pragma unroll
    for (int i = 0; i < 4; i++) pk.h[i] = __float2bfloat16(tile[cg + i][r]);
    *(uint2*)&dst[(size_t)(p0 + r) * ND + o0 + cg] = pk.u;
}

// ---------------- K2: h1[hl][row][o] = relu(x@W1 + b1) in bf16
__global__ void h1_kernel(const float* __restrict__ x, const float* __restrict__ W1,
                          const float* __restrict__ b1, __hip_bfloat16* __restrict__ h1buf,
                          int headBase, int rowBase, int rowsPerIter) {
    int t = threadIdx.x;
    int hl = blockIdx.y;
    int h = headBase + hl;
    int rl = (blockIdx.x << 1) + (t >> 7);
    int b = rowBase + rl;
    int o0 = (t & 127) << 3;
    float4 xv = *(const float4*)&x[(size_t)b * 4];
    const float* xf = (const float*)&xv;
    const float* Wh = W1 + (size_t)h * 4 * ND;
    float acc[8];
    {
        float4 b0 = *(const float4*)&b1[h * ND + o0];
        float4 b4 = *(const float4*)&b1[h * ND + o0 + 4];
        acc[0] = b0.x; acc[1] = b0.y; acc[2] = b0.z; acc[3] = b0.w;
        acc[4] = b4.x; acc[5] = b4.y; acc[6] = b4.z; acc[7] = b4.w;
    }
#pragma unroll
    for (int f = 0; f < 4; f++) {
        float4 w0 = *(const float4*)&Wh[f * ND + o0];
        float4 w4 = *(const float4*)&Wh[f * ND + o0 + 4];
        float s = xf[f];
        acc[0] += s * w0.x; acc[1] += s * w0.y; acc[2] += s * w0.z; acc[3] += s * w0.w;
        acc[4] += s * w4.x; acc[5] += s * w4.y; acc[6] += s * w4.z; acc[7] += s * w4.w;
    }
    union { __hip_bfloat16 hh[8]; uint4 u; } pk;
#pragma unroll
    for (int i = 0; i < 8; i++) {
        float v = acc[i] > 0.f ? acc[i] : 0.f;
        pk.hh[i] = __float2bfloat16(v);
    }
    *(uint4*)&h1buf[((size_t)hl * rowsPerIter + rl) * ND + o0] = pk.u;
}

// ---------------- K3: fused GEMM (h1 @ W2xT) + bias + relu + contract W3x -> atomic Acc
__global__ __launch_bounds__(256) void gemm_kernel(
    const __hip_bfloat16* __restrict__ h1buf,
    const __hip_bfloat16* __restrict__ W21T, const __hip_bfloat16* __restrict__ W22T,
    const float* __restrict__ b21, const float* __restrict__ b22,
    const float* __restrict__ W31, const float* __restrict__ W32,
    float* __restrict__ Acc31, float* __restrict__ Acc32,
    int headBase, int rowBase, int rowsPerIter) {
    __shared__ __hip_bfloat16 Als[128 * 32];
    __shared__ __hip_bfloat16 Bls[128 * 32];
    __shared__ float red[256];

    const int nt = blockIdx.x;
    const int mt = blockIdx.y;
    const int hl = blockIdx.z;
    const int h = headBase + hl;
    const bool is21 = nt < 8;
    const int ncol0 = (nt & 7) << 7;
    const int tid = threadIdx.x;
    const int lane = tid & 63;
    const int wid = tid >> 6;
    const int wr = wid >> 1, wc = wid & 1;

    const char* Abase = (const char*)(h1buf + ((size_t)hl * rowsPerIter + (size_t)mt * 128) * ND);
    const __hip_bfloat16* WTsel = (is21 ? W21T : W22T) + (size_t)h * ND * ND + (size_t)ncol0 * ND;
    const char* Bbase = (const char*)WTsel;

    f32x4 acc[4][4];
#pragma unroll
    for (int m = 0; m < 4; m++)
#pragma unroll
        for (int n = 0; n < 4; n++) acc[m][n] = (f32x4){0.f, 0.f, 0.f, 0.f};

    const int sg_row = (wid * 32) + (lane >> 2);
    const int sg_off = (lane & 3) * 16;
    char* AlsW = (char*)Als + wid * 2048;  // wave-uniform LDS base (HW adds lane*16)
    char* BlsW = (char*)Bls + wid * 2048;

    for (int k = 0; k < ND; k += 32) {
        const char* as = Abase + (size_t)sg_row * 2048 + k * 2 + sg_off;
        const char* bs = Bbase + (size_t)sg_row * 2048 + k * 2 + sg_off;
        load16_lds(as, AlsW);
        load16_lds(as + 16 * 2048, AlsW + 1024);
        load16_lds(bs, BlsW);
        load16_lds(bs + 16 * 2048, BlsW + 1024);
        __syncthreads();
        bf16x8 af[4], bfr[4];
        const char* Ar = (const char*)Als + ((wr * 64 + (lane & 15)) * 64) + ((lane >> 4) * 16);
        const char* Br = (const char*)Bls + ((wc * 64 + (lane & 15)) * 64) + ((lane >> 4) * 16);
#pragma unroll
        for (int m = 0; m < 4; m++) af[m] = *(const bf16x8*)(Ar + m * 16 * 64);
#pragma unroll
        for (int n = 0; n < 4; n++) bfr[n] = *(const bf16x8*)(Br + n * 16 * 64);
#pragma unroll
        for (int m = 0; m < 4; m++)
#pragma unroll
            for (int n = 0; n < 4; n++)
                acc[m][n] = __builtin_amdgcn_mfma_f32_16x16x32_bf16(af[m], bfr[n], acc[m][n], 0, 0, 0);
        __syncthreads();
    }

    // epilogue: v = relu(acc + b2[col]); partial[c] = sum_cols v*W3[col][c]
    red[tid] = 0.f;
    __syncthreads();
    const float* b2 = (is21 ? b21 : b22) + h * ND + ncol0;
    const float* W3 = (is21 ? W31 : W32) + h * ND * 2 + ncol0 * 2;
    float bias[4], w3a[4], w3b[4];
#pragma unroll
    for (int n = 0; n < 4; n++) {
        int cl = wc * 64 + n * 16 + (lane & 15);
        bias[n] = b2[cl];
        w3a[n] = W3[cl * 2 + 0];
        w3b[n] = W3[cl * 2 + 1];
    }
#pragma unroll
    for (int m = 0; m < 4; m++) {
#pragma unroll
        for (int j = 0; j < 4; j++) {
            float s0 = 0.f, s1 = 0.f;
#pragma unroll
            for (int n = 0; n < 4; n++) {
                float v = acc[m][n][j] + bias[n];
                v = v > 0.f ? v : 0.f;
                s0 += v * w3a[n];
                s1 += v * w3b[n];
            }
            s0 += __shfl_xor(s0, 1); s0 += __shfl_xor(s0, 2);
            s0 += __shfl_xor(s0, 4); s0 += __shfl_xor(s0, 8);
            s1 += __shfl_xor(s1, 1); s1 += __shfl_xor(s1, 2);
            s1 += __shfl_xor(s1, 4); s1 += __shfl_xor(s1, 8);
            if ((lane & 15) == 0) {
                int rl = wr * 64 + m * 16 + ((lane >> 4) << 2) + j;
                atomicAdd(&red[rl * 2 + 0], s0);
                atomicAdd(&red[rl * 2 + 1], s1);
            }
        }
    }
    __syncthreads();
    float* Acc = (is21 ? Acc31 : Acc32) + ((size_t)h * NB + rowBase + (size_t)mt * 128) * 2;
    atomicAdd(&Acc[tid], red[tid]);
}

// ---------------- K4: QP math + head combine
__global__ void final_kernel(const float* __restrict__ x,
                             const float* __restrict__ Acc31, const float* __restrict__ Acc32,
                             const float* __restrict__ b31, const float* __restrict__ b32,
                             const float* __restrict__ wt, const float* __restrict__ mean,
                             const float* __restrict__ stdv, float* __restrict__ out) {
    int b = blockIdx.x * 256 + threadIdx.x;
    float4 xv = *(const float4*)&x[(size_t)b * 4];
    float px = xv.x * stdv[0] + mean[0];
    float py = xv.y * stdv[1] + mean[1];
    float th = xv.z * stdv[2] + mean[2];
    float v  = xv.w * stdv[3] + mean[3];
    float st = sinf(th), ct = cosf(th);
    float dx = px - 40.f, dy = py - 15.f;
    float barrier = dx * dx + dy * dy - 36.f;
    float bdot = 2.f * dx * v * ct + 2.f * dy * v * st;
    float Lf2b = 2.f * v * v;
    float L1 = -2.f * dx * v * st + 2.f * dy * v * ct;
    float L2 = 2.f * dx * ct + 2.f * dy * st;
    float G0 = -L1, G1 = -L2;
    float GG = G0 * G0 + G1 * G1;

    float wv[NH];
    float mx = -1e30f;
#pragma unroll
    for (int h = 0; h < NH; h++) { wv[h] = wt[h]; mx = wv[h] > mx ? wv[h] : mx; }
    float ssum = 0.f;
#pragma unroll
    for (int h = 0; h < NH; h++) { wv[h] = expf(wv[h] - mx); ssum += wv[h]; }
    float winv = 1.f / ssum;

    float out0 = 0.f, out1 = 0.f, p1 = 0.f;
#pragma unroll
    for (int h = 0; h < NH; h++) {
        float2 a31 = *(const float2*)&Acc31[((size_t)h * NB + b) * 2];
        float2 a32 = *(const float2*)&Acc32[((size_t)h * NB + b) * 2];
        float x31_0 = a31.x + b31[h * 2 + 0];
        float x31_1 = a31.y + b31[h * 2 + 1];
        float s0 = 4.f / (1.f + expf(-(a32.x + b32[h * 2 + 0])));
        float a;
        if (h == 0) {
            p1 = s0;
            a = 4.f / (1.f + expf(-(a32.y + b32[1])));
        } else {
            a = s0;
        }
        float hqp = Lf2b + (p1 + a) * bdot + p1 * a * barrier;
        float z0 = -x31_0, z1 = -x31_1;
        float gz = G0 * z0 + G1 * z1;
        float lam = gz - hqp;
        lam = lam > 0.f ? lam : 0.f;
        lam = lam / (GG + 1e-12f);
        float u0 = z0 - lam * G0, u1 = z1 - lam * G1;
        float w = wv[h] * winv;
        out0 += w * u0;
        out1 += w * u1;
    }
    *(float2*)&out[(size_t)b * 2] = (float2){out0, out1};
}

static inline int imin(int a, int b) { return a < b ? a : b; }

extern "C" void kernel_launch(void* const* d_in, const int* in_sizes, int n_in,
                              void* d_out, int out_size, void* d_ws, size_t ws_size,
                              hipStream_t stream) {
    const float* x    = (const float*)d_in[0];
    const float* W1   = (const float*)d_in[1];
    const float* b1   = (const float*)d_in[2];
    const float* W21  = (const float*)d_in[3];
    const float* b21  = (const float*)d_in[4];
    const float* W22  = (const float*)d_in[5];
    const float* b22  = (const float*)d_in[6];
    const float* W31  = (const float*)d_in[7];
    const float* b31  = (const float*)d_in[8];
    const float* W32  = (const float*)d_in[9];
    const float* b32  = (const float*)d_in[10];
    const float* wt   = (const float*)d_in[11];
    const float* mean = (const float*)d_in[12];
    const float* stdv = (const float*)d_in[13];
    float* out = (float*)d_out;

    char* ws = (char*)d_ws;
    size_t off = 0;
    const size_t WT_bytes = (size_t)NH * ND * ND * 2;
    __hip_bfloat16* W21T = (__hip_bfloat16*)(ws + off); off += WT_bytes;
    __hip_bfloat16* W22T = (__hip_bfloat16*)(ws + off); off += WT_bytes;
    const size_t Acc_bytes = (size_t)NH * NB * 2 * 4;
    float* Acc31 = (float*)(ws + off); off += Acc_bytes;
    float* Acc32 = (float*)(ws + off); off += Acc_bytes;
    __hip_bfloat16* h1buf = (__hip_bfloat16*)(ws + off);
    size_t avail = (ws_size > off) ? (ws_size - off) : 0;

    const size_t perHead = (size_t)NB * ND * 2;
    int headsPerIter, rowsPerIter;
    if (avail >= (size_t)NH * perHead) {
        headsPerIter = NH; rowsPerIter = NB;
    } else if (avail >= perHead) {
        headsPerIter = (int)(avail / perHead); rowsPerIter = NB;
    } else {
        headsPerIter = 1;
        size_t rows = (avail / (ND * 2)) & ~(size_t)127;
        rowsPerIter = (int)rows;
        if (rowsPerIter < 128) rowsPerIter = 128;  // last-ditch; ws assumed >= ~50MB
    }

    hipMemsetAsync(Acc31, 0, Acc_bytes * 2, stream);
    wt_kernel<<<dim3(32, 32, 2 * NH), 256, 0, stream>>>(W21, W22, W21T, W22T);

    for (int h0 = 0; h0 < NH; h0 += headsPerIter) {
        int hs = imin(headsPerIter, NH - h0);
        for (int r0 = 0; r0 < NB; r0 += rowsPerIter) {
            int rows = imin(rowsPerIter, NB - r0);
            h1_kernel<<<dim3(rows / 2, hs), 256, 0, stream>>>(x, W1, b1, h1buf, h0, r0, rowsPerIter);
            gemm_kernel<<<dim3(16, rows / 128, hs), 256, 0, stream>>>(
                h1buf, W21T, W22T, b21, b22, W31, W32, Acc31, Acc32, h0, r0, rowsPerIter);
        }
    }
    final_kernel<<<dim3(NB / 256), 256, 0, stream>>>(x, Acc31, Acc32, b31, b32, wt, mean, stdv, out);
}

// Round 2
// 1723.838 us; speedup vs baseline: 1.2017x; 1.2017x over previous
//
#include <hip/hip_runtime.h>
#include <hip/hip_bf16.h>
#include <stdint.h>

#define NH 10
#define NB 32768
#define ND 1024

typedef __bf16 bf16x8 __attribute__((ext_vector_type(8)));
typedef float f32x4 __attribute__((ext_vector_type(4)));

typedef const __attribute__((address_space(1))) unsigned int* gas_ptr;
typedef __attribute__((address_space(3))) unsigned int* las_ptr;

__device__ __forceinline__ void load16_lds(const void* g, void* l) {
    __builtin_amdgcn_global_load_lds((gas_ptr)g, (las_ptr)l, 16, 0, 0);
}

#define BAR() asm volatile("s_barrier" ::: "memory")
#define WAITV4() asm volatile("s_waitcnt vmcnt(4)" ::: "memory")
#define WAITV0() asm volatile("s_waitcnt vmcnt(0)" ::: "memory")

// ---------------- K1: transpose + convert W21/W22 (H,1024,1024 f32 [o][p]) -> bf16 [p][o]
__global__ void wt_kernel(const float* __restrict__ W21, const float* __restrict__ W22,
                          __hip_bfloat16* __restrict__ W21T, __hip_bfloat16* __restrict__ W22T) {
    int z = blockIdx.z;
    const float* src;
    __hip_bfloat16* dst;
    if (z < NH) { src = W21 + (size_t)z * ND * ND; dst = W21T + (size_t)z * ND * ND; }
    else        { src = W22 + (size_t)(z - NH) * ND * ND; dst = W22T + (size_t)(z - NH) * ND * ND; }
    int o0 = blockIdx.x * 32, p0 = blockIdx.y * 32;
    __shared__ float tile[32][33];
    int t = threadIdx.x;
    int r = t >> 3, cg = (t & 7) << 2;
    float4 v = *(const float4*)&src[(size_t)(o0 + r) * ND + p0 + cg];
    tile[r][cg + 0] = v.x; tile[r][cg + 1] = v.y; tile[r][cg + 2] = v.z; tile[r][cg + 3] = v.w;
    __syncthreads();
    union { __hip_bfloat16 h[4]; uint2 u; } pk;
#pragma unroll
    for (int i = 0; i < 4; i++) pk.h[i] = __float2bfloat16(tile[cg + i][r]);
    *(uint2*)&dst[(size_t)(p0 + r) * ND + o0 + cg] = pk.u;
}

// ---------------- K2: h1[hl][row][o] = relu(x@W1 + b1) in bf16
__global__ void h1_kernel(const float* __restrict__ x, const float* __restrict__ W1,
                          const float* __restrict__ b1, __hip_bfloat16* __restrict__ h1buf,
                          int headBase, int rowBase, int rowsPerIter) {
    int t = threadIdx.x;
    int hl = blockIdx.y;
    int h = headBase + hl;
    int rl = (blockIdx.x << 1) + (t >> 7);
    int b = rowBase + rl;
    int o0 = (t & 127) << 3;
    float4 xv = *(const float4*)&x[(size_t)b * 4];
    const float* xf = (const float*)&xv;
    const float* Wh = W1 + (size_t)h * 4 * ND;
    float acc[8];
    {
        float4 b0 = *(const float4*)&b1[h * ND + o0];
        float4 b4 = *(const float4*)&b1[h * ND + o0 + 4];
        acc[0] = b0.x; acc[1] = b0.y; acc[2] = b0.z; acc[3] = b0.w;
        acc[4] = b4.x; acc[5] = b4.y; acc[6] = b4.z; acc[7] = b4.w;
    }
#pragma unroll
    for (int f = 0; f < 4; f++) {
        float4 w0 = *(const float4*)&Wh[f * ND + o0];
        float4 w4 = *(const float4*)&Wh[f * ND + o0 + 4];
        float s = xf[f];
        acc[0] += s * w0.x; acc[1] += s * w0.y; acc[2] += s * w0.z; acc[3] += s * w0.w;
        acc[4] += s * w4.x; acc[5] += s * w4.y; acc[6] += s * w4.z; acc[7] += s * w4.w;
    }
    union { __hip_bfloat16 hh[8]; uint4 u; } pk;
#pragma unroll
    for (int i = 0; i < 8; i++) {
        float v = acc[i] > 0.f ? acc[i] : 0.f;
        pk.hh[i] = __float2bfloat16(v);
    }
    *(uint4*)&h1buf[((size_t)hl * rowsPerIter + rl) * ND + o0] = pk.u;
}

// ---------------- K3: 256x256x64 8-phase fused GEMM + relu + W3 contract -> atomic Acc
// LDS layout per matrix: [2 buf][2 khalf][256 rows][4 chunks][16B], chunk XOR-swizzled
// with ((row>>1)&3). Staging: linear LDS dest + pre-swizzled per-lane global source.
__global__ __launch_bounds__(512, 2) void gemm_kernel(
    const __hip_bfloat16* __restrict__ h1buf,
    const __hip_bfloat16* __restrict__ W21T, const __hip_bfloat16* __restrict__ W22T,
    const float* __restrict__ b21, const float* __restrict__ b22,
    const float* __restrict__ W31, const float* __restrict__ W32,
    float* __restrict__ Acc31, float* __restrict__ Acc32,
    int headBase, int rowBase, int rowsPerIter, int Mtiles) {
    __shared__ char lds[131072];
    char* ldsA = lds;
    char* ldsB = lds + 65536;

    const int t = threadIdx.x;
    const int lane = t & 63, wid = t >> 6;
    const int wr = wid >> 2, wc = wid & 3;
    const int rb = lane & 15;

    // XCD-chunked bijective block swizzle (nblk % 8 == 0 by construction)
    const int nblk = gridDim.x;
    const int orig = blockIdx.x;
    const int wg = (orig & 7) * (nblk >> 3) + (orig >> 3);
    const int perHead = Mtiles << 3;
    const int hl = wg / perHead;
    const int rem = wg - hl * perHead;
    const int mt = rem >> 3;
    const int nt = rem & 7;
    const int h = headBase + hl;
    const bool is21 = nt < 4;
    const int ncol = (nt & 3) << 8;

    // per-thread staging source (pre-swizzled chunk), row = t>>2 (+128 for 2nd load)
    const int cswz = ((t & 3) ^ ((t >> 3) & 3)) << 4;
    const char* Asrc = (const char*)h1buf +
        (((size_t)hl * rowsPerIter + (size_t)mt * 256 + (t >> 2)) * 2048) + cswz;
    const __hip_bfloat16* Wsel = is21 ? W21T : W22T;
    const char* Bsrc = (const char*)Wsel +
        (((size_t)h * 1024 + ncol + (t >> 2)) * 2048) + cswz;

    // ds_read fragment offsets (swizzled)
    const int swz16 = ((lane >> 4) ^ ((rb >> 1) & 3)) << 4;
    const int aRow = (wr * 128 + rb) * 64 + swz16;
    const int bRow = (wc * 64 + rb) * 64 + swz16;

    f32x4 acc[8][4];
#pragma unroll
    for (int m = 0; m < 8; m++)
#pragma unroll
        for (int n = 0; n < 4; n++) acc[m][n] = (f32x4){0.f, 0.f, 0.f, 0.f};
    bf16x8 af[4], bq[4];

#define GLA(bufb, kh, kt) do { \
    load16_lds(Asrc + (size_t)(kt) * 128 + (kh) * 64, ldsA + (bufb) * 32768 + (kh) * 16384 + wid * 1024); \
    load16_lds(Asrc + 262144 + (size_t)(kt) * 128 + (kh) * 64, ldsA + (bufb) * 32768 + (kh) * 16384 + 8192 + wid * 1024); } while (0)
#define GLB(bufb, kh, kt) do { \
    load16_lds(Bsrc + (size_t)(kt) * 128 + (kh) * 64, ldsB + (bufb) * 32768 + (kh) * 16384 + wid * 1024); \
    load16_lds(Bsrc + 262144 + (size_t)(kt) * 128 + (kh) * 64, ldsB + (bufb) * 32768 + (kh) * 16384 + 8192 + wid * 1024); } while (0)
#define LDB(bufb, ks) { const char* p_ = ldsB + (bufb) * 32768 + (ks) * 16384 + bRow; \
    bq[0] = *(const bf16x8*)(p_); bq[1] = *(const bf16x8*)(p_ + 1024); \
    bq[2] = *(const bf16x8*)(p_ + 2048); bq[3] = *(const bf16x8*)(p_ + 3072); }
#define LDA(bufb, ks, mg) { const char* p_ = ldsA + (bufb) * 32768 + (ks) * 16384 + (mg) * 4096 + aRow; \
    af[0] = *(const bf16x8*)(p_); af[1] = *(const bf16x8*)(p_ + 1024); \
    af[2] = *(const bf16x8*)(p_ + 2048); af[3] = *(const bf16x8*)(p_ + 3072); }
#define FMA16(mg) { \
    __builtin_amdgcn_s_setprio(1); \
    _Pragma("unroll") for (int i_ = 0; i_ < 4; ++i_) \
        _Pragma("unroll") for (int n_ = 0; n_ < 4; ++n_) \
            acc[(mg) * 4 + i_][n_] = __builtin_amdgcn_mfma_f32_16x16x32_bf16(af[i_], bq[n_], acc[(mg) * 4 + i_][n_], 0, 0, 0); \
    __builtin_amdgcn_s_setprio(0); }

    // prologue: stage tile 0 fully; wait kh0 halves (4 oldest of 8)
    GLA(0, 0, 0); GLB(0, 0, 0); GLA(0, 1, 0); GLB(0, 1, 0);
    WAITV4();
    BAR();

    int buf = 0;
    for (int T = 0; T < 15; ++T) {
        // phase 0: stage A.kh0 of T+1; compute kh0, m0-3
        GLA(buf ^ 1, 0, T + 1);
        LDB(buf, 0); LDA(buf, 0, 0);
        BAR(); FMA16(0); BAR();
        // phase 1: stage B.kh0 of T+1; compute kh0, m4-7; guarantee this tile's kh1
        GLB(buf ^ 1, 0, T + 1);
        LDA(buf, 0, 1);
        WAITV4(); BAR(); FMA16(1); BAR();
        // phase 2: stage A.kh1 of T+1; compute kh1, m0-3
        GLA(buf ^ 1, 1, T + 1);
        LDB(buf, 1); LDA(buf, 1, 0);
        BAR(); FMA16(0); BAR();
        // phase 3: stage B.kh1 of T+1; compute kh1, m4-7; guarantee next tile's kh0
        GLB(buf ^ 1, 1, T + 1);
        LDA(buf, 1, 1);
        WAITV4(); BAR(); FMA16(1); BAR();
        buf ^= 1;
    }
    // tail tile (T=15): no staging
    LDB(buf, 0); LDA(buf, 0, 0); BAR(); FMA16(0); BAR();
    LDA(buf, 0, 1); WAITV0(); BAR(); FMA16(1); BAR();
    LDB(buf, 1); LDA(buf, 1, 0); BAR(); FMA16(0); BAR();
    LDA(buf, 1, 1); BAR(); FMA16(1); BAR();

    // ---- epilogue: relu(acc+bias) . W3 -> per-row (s0,s1), block-reduce, atomic
    float* red = (float*)lds;  // 256 rows x 2 = 512 floats (reuse A-buffer region)
    __syncthreads();
    red[t] = 0.f;
    __syncthreads();

    const float* b2 = (is21 ? b21 : b22) + h * ND + ncol;
    const float* W3 = (is21 ? W31 : W32) + (size_t)h * ND * 2 + ncol * 2;
    float bias[4], w3a[4], w3b[4];
#pragma unroll
    for (int n = 0; n < 4; n++) {
        int cl = wc * 64 + n * 16 + rb;
        bias[n] = b2[cl];
        w3a[n] = W3[cl * 2 + 0];
        w3b[n] = W3[cl * 2 + 1];
    }
#pragma unroll
    for (int m = 0; m < 8; m++) {
#pragma unroll
        for (int j = 0; j < 4; j++) {
            float s0 = 0.f, s1 = 0.f;
#pragma unroll
            for (int n = 0; n < 4; n++) {
                float v = acc[m][n][j] + bias[n];
                v = v > 0.f ? v : 0.f;
                s0 += v * w3a[n];
                s1 += v * w3b[n];
            }
            s0 += __shfl_xor(s0, 1); s0 += __shfl_xor(s0, 2);
            s0 += __shfl_xor(s0, 4); s0 += __shfl_xor(s0, 8);
            s1 += __shfl_xor(s1, 1); s1 += __shfl_xor(s1, 2);
            s1 += __shfl_xor(s1, 4); s1 += __shfl_xor(s1, 8);
            if (rb == 0) {
                int row = wr * 128 + m * 16 + ((lane >> 4) << 2) + j;
                atomicAdd(&red[row * 2 + 0], s0);
                atomicAdd(&red[row * 2 + 1], s1);
            }
        }
    }
    __syncthreads();
    float* Acc = (is21 ? Acc31 : Acc32) + ((size_t)h * NB + rowBase + (size_t)mt * 256) * 2;
    atomicAdd(&Acc[t], red[t]);
#undef GLA
#undef GLB
#undef LDB
#undef LDA
#undef FMA16
}

// ---------------- K4: QP math + head combine
__global__ void final_kernel(const float* __restrict__ x,
                             const float* __restrict__ Acc31, const float* __restrict__ Acc32,
                             const float* __restrict__ b31, const float* __restrict__ b32,
                             const float* __restrict__ wt, const float* __restrict__ mean,
                             const float* __restrict__ stdv, float* __restrict__ out) {
    int b = blockIdx.x * 256 + threadIdx.x;
    float4 xv = *(const float4*)&x[(size_t)b * 4];
    float px = xv.x * stdv[0] + mean[0];
    float py = xv.y * stdv[1] + mean[1];
    float th = xv.z * stdv[2] + mean[2];
    float v  = xv.w * stdv[3] + mean[3];
    float st = sinf(th), ct = cosf(th);
    float dx = px - 40.f, dy = py - 15.f;
    float barrier = dx * dx + dy * dy - 36.f;
    float bdot = 2.f * dx * v * ct + 2.f * dy * v * st;
    float Lf2b = 2.f * v * v;
    float L1 = -2.f * dx * v * st + 2.f * dy * v * ct;
    float L2 = 2.f * dx * ct + 2.f * dy * st;
    float G0 = -L1, G1 = -L2;
    float GG = G0 * G0 + G1 * G1;

    float wv[NH];
    float mx = -1e30f;
#pragma unroll
    for (int h = 0; h < NH; h++) { wv[h] = wt[h]; mx = wv[h] > mx ? wv[h] : mx; }
    float ssum = 0.f;
#pragma unroll
    for (int h = 0; h < NH; h++) { wv[h] = expf(wv[h] - mx); ssum += wv[h]; }
    float winv = 1.f / ssum;

    float out0 = 0.f, out1 = 0.f, p1 = 0.f;
#pragma unroll
    for (int h = 0; h < NH; h++) {
        float2 a31 = *(const float2*)&Acc31[((size_t)h * NB + b) * 2];
        float2 a32 = *(const float2*)&Acc32[((size_t)h * NB + b) * 2];
        float x31_0 = a31.x + b31[h * 2 + 0];
        float x31_1 = a31.y + b31[h * 2 + 1];
        float s0 = 4.f / (1.f + expf(-(a32.x + b32[h * 2 + 0])));
        float a;
        if (h == 0) {
            p1 = s0;
            a = 4.f / (1.f + expf(-(a32.y + b32[1])));
        } else {
            a = s0;
        }
        float hqp = Lf2b + (p1 + a) * bdot + p1 * a * barrier;
        float z0 = -x31_0, z1 = -x31_1;
        float gz = G0 * z0 + G1 * z1;
        float lam = gz - hqp;
        lam = lam > 0.f ? lam : 0.f;
        lam = lam / (GG + 1e-12f);
        float u0 = z0 - lam * G0, u1 = z1 - lam * G1;
        float w = wv[h] * winv;
        out0 += w * u0;
        out1 += w * u1;
    }
    *(float2*)&out[(size_t)b * 2] = (float2){out0, out1};
}

static inline int imin(int a, int b) { return a < b ? a : b; }

extern "C" void kernel_launch(void* const* d_in, const int* in_sizes, int n_in,
                              void* d_out, int out_size, void* d_ws, size_t ws_size,
                              hipStream_t stream) {
    const float* x    = (const float*)d_in[0];
    const float* W1   = (const float*)d_in[1];
    const float* b1   = (const float*)d_in[2];
    const float* W21  = (const float*)d_in[3];
    const float* b21  = (const float*)d_in[4];
    const float* W22  = (const float*)d_in[5];
    const float* b22  = (const float*)d_in[6];
    const float* W31  = (const float*)d_in[7];
    const float* b31  = (const float*)d_in[8];
    const float* W32  = (const float*)d_in[9];
    const float* b32  = (const float*)d_in[10];
    const float* wt   = (const float*)d_in[11];
    const float* mean = (const float*)d_in[12];
    const float* stdv = (const float*)d_in[13];
    float* out = (float*)d_out;

    char* ws = (char*)d_ws;
    size_t off = 0;
    const size_t WT_bytes = (size_t)NH * ND * ND * 2;
    __hip_bfloat16* W21T = (__hip_bfloat16*)(ws + off); off += WT_bytes;
    __hip_bfloat16* W22T = (__hip_bfloat16*)(ws + off); off += WT_bytes;
    const size_t Acc_bytes = (size_t)NH * NB * 2 * 4;
    float* Acc31 = (float*)(ws + off); off += Acc_bytes;
    float* Acc32 = (float*)(ws + off); off += Acc_bytes;
    __hip_bfloat16* h1buf = (__hip_bfloat16*)(ws + off);
    size_t avail = (ws_size > off) ? (ws_size - off) : 0;

    const size_t perHead = (size_t)NB * ND * 2;
    int headsPerIter, rowsPerIter;
    if (avail >= (size_t)NH * perHead) {
        headsPerIter = NH; rowsPerIter = NB;
    } else if (avail >= perHead) {
        headsPerIter = (int)(avail / perHead); rowsPerIter = NB;
    } else {
        headsPerIter = 1;
        size_t rows = (avail / (ND * 2)) & ~(size_t)255;
        rowsPerIter = (int)rows;
        if (rowsPerIter < 256) rowsPerIter = 256;  // last-ditch; ws assumed >= ~50MB
    }

    hipMemsetAsync(Acc31, 0, Acc_bytes * 2, stream);
    wt_kernel<<<dim3(32, 32, 2 * NH), 256, 0, stream>>>(W21, W22, W21T, W22T);

    for (int h0 = 0; h0 < NH; h0 += headsPerIter) {
        int hs = imin(headsPerIter, NH - h0);
        for (int r0 = 0; r0 < NB; r0 += rowsPerIter) {
            int rows = imin(rowsPerIter, NB - r0);
            int Mtiles = rows / 256;
            h1_kernel<<<dim3(rows / 2, hs), 256, 0, stream>>>(x, W1, b1, h1buf, h0, r0, rowsPerIter);
            gemm_kernel<<<dim3(8 * Mtiles * hs), 512, 0, stream>>>(
                h1buf, W21T, W22T, b21, b22, W31, W32, Acc31, Acc32, h0, r0, rowsPerIter, Mtiles);
        }
    }
    final_kernel<<<dim3(NB / 256), 256, 0, stream>>>(x, Acc31, Acc32, b31, b32, wt, mean, stdv, out);
}